// Round 6
// baseline (3933.727 us; speedup 1.0000x reference)
//
#include <hip/hip_runtime.h>
#include <hip/hip_bf16.h>

#define BB   1024
#define TT   64
#define IND  64
#define HH   512
#define G4   2048   // 4*H
#define NLAYER 8
#define NCLS 128
#define KP   1024   // packed W k-stride: k<512 = W_hh, k>=512 = W_ih (layer0 64 + pad)
#define RS   8      // ring slots per layer (reuse distance 8 = fence period)
#define SLOT (32 * 1024 * 16)  // elements per h slot: [by=32][b=1024][jj=16]

typedef __bf16 bf16x8 __attribute__((ext_vector_type(8)));
typedef float  f32x4  __attribute__((ext_vector_type(4)));

typedef const __attribute__((address_space(1))) void* as1cvp;
typedef __attribute__((address_space(3))) void* as3vp;

__device__ __forceinline__ void gload16(void* lds, const void* g) {
  __builtin_amdgcn_global_load_lds((as1cvp)g, (as3vp)lds, 16, 0, 0);
}

__device__ __forceinline__ float sigmf(float x) { return 1.f / (1.f + __expf(-x)); }
__device__ __forceinline__ float tanhfast(float x) { return 2.f / (1.f + __expf(-2.f * x)) - 1.f; }

// ---------------- prep kernels ----------------
__global__ void cvt_kernel(const float* __restrict__ s, __bf16* __restrict__ d, int n) {
  int i = blockIdx.x * 256 + threadIdx.x;
  if (i < n) d[i] = (__bf16)s[i];
}

__global__ void pack_w(const float* __restrict__ whh0, const float* __restrict__ wih0,
                       const float* __restrict__ whh, const float* __restrict__ wih,
                       __bf16* __restrict__ Wp) {
  int i = blockIdx.x * 256 + threadIdx.x;  // 8*2048*1024
  int k = i & (KP - 1), n = (i >> 10) & 2047, l = i >> 21;
  float v;
  if (k < 512) v = (l == 0) ? whh0[n * 512 + k] : whh[((size_t)(l - 1) * G4 + n) * 512 + k];
  else if (l == 0) v = (k < 512 + IND) ? wih0[n * IND + (k - 512)] : 0.f;
  else v = wih[((size_t)(l - 1) * G4 + n) * 512 + (k - 512)];
  Wp[i] = (__bf16)v;
}

__global__ void bias_prep(const float* __restrict__ bi0, const float* __restrict__ bh0,
                          const float* __restrict__ bi, const float* __restrict__ bh,
                          float* __restrict__ biasb) {
  int i = blockIdx.x * 256 + threadIdx.x;  // 8*2048
  int l = i >> 11, k = i & 2047;
  float v = (l == 0) ? (bi0[k] + bh0[k]) : (bi[(l - 1) * G4 + k] + bh[(l - 1) * G4 + k]);
  biasb[i] = v;
}

__global__ void zero_u32(unsigned* __restrict__ p, int n) {
  int i = blockIdx.x * 256 + threadIdx.x;
  if (i < n) p[i] = 0u;
}

// ---------------- all-layers pipelined LSTM ----------------
// R16 = R14 (proven 3643us) + SCOPE-SPLIT h stores.
// Diagnosis: agent-scope atomic stores write THROUGH the per-XCD L2 (L2 is not
// device-coherent, so device-visible data cannot allocate locally). Hence the
// h-part A-reads — produced on the SAME XCD one step earlier — always miss L2
// and pay fabric/IF$ latency (~450-900cy) that the 620cy half-kt cover can't
// hide. That is the ~30us/step of stall that survived R12/R14/R15 pipelining.
// Fix: each h value has two consumers with different scope needs:
//   (a) own layer's h-part (same XCD)  -> NORMAL store into ringH, a 2-slot
//       per-layer ring (2MB/XCD, L2-resident; reads become local L2 hits)
//   (b) downstream x-part (cross-XCD)  -> agent store into ringX (unchanged)
// Layer 7: normal store to h7 only (own h-part + post-kernel FC both covered).
// Coherence: ringH reuses an address every 2 steps -> acquire-agent fence is
// now UNCONDITIONAL per step (strictly stronger than the per-8 cadence; also
// still covers ringX's 8-step reuse). ringH overwrite safety: own-flag>=t at
// B1 certifies all own-group blocks finished h-part(t-1), which read slot
// (t-2)&1 -> overwriting slot t&1 at step t is safe. B3's vmcnt drain orders
// both store types before the flag. Same MFMA order and values ->
// bit-identical numerics to R14.
__global__ __launch_bounds__(256, 2) void lstm_all(
    const float* __restrict__ xf,      // [B][T][64] fp32
    const __bf16* __restrict__ Wp,     // [8][2048][KP]
    const float* __restrict__ biasb,   // [8][2048]
    __bf16* __restrict__ hring,        // [7][RS][SLOT]   cross-XCD ring (agent)
    __bf16* __restrict__ hringH,       // [7][2][SLOT]    own-XCD ring (normal)
    __bf16* __restrict__ h7,           // [64][SLOT]
    unsigned* __restrict__ flags,      // [8][2][64] (32 used per group)
    unsigned* __restrict__ xslot) {    // [8]
  extern __shared__ __bf16 Wlds[];     // 64KB: 16 k-slices x (64 rows x 32 k)
  __shared__ int sbs;
  const int tid = threadIdx.x;

  if (tid == 0) {
    unsigned xcc;
    asm volatile("s_getreg_b32 %0, hwreg(HW_REG_XCC_ID)" : "=s"(xcc));
    xcc &= 7u;
    unsigned slot = __hip_atomic_fetch_add(xslot + xcc, 1u, __ATOMIC_RELAXED,
                                           __HIP_MEMORY_SCOPE_AGENT) & 63u;
    sbs = (int)((xcc << 6) | slot);
  }
  __syncthreads();
  const int l  = sbs >> 6;         // layer = XCD
  const int bx = (sbs >> 5) & 1;   // b-half (512 rows)
  const int by = sbs & 31;         // j-tile (16 j x 4 gates)
  const int j0 = by << 4;
  const __bf16* Wl = Wp + (size_t)l * G4 * KP;

  // ---- stage W_hh (64 n-rows x 512 k) into LDS, XOR-swizzled
  for (int it = 0; it < 16; ++it) {
    const int p = it * 256 + tid;           // granule 0..4095
    const int kt = p >> 8;
    const int q = p & 255;
    const int u = q >> 2;                   // row 0..63 (gate*16+jj)
    const int g = (q & 3) ^ ((u >> 1) & 3);
    const int n = ((u >> 4) << 9) + j0 + (u & 15);
    gload16(&Wlds[p * 8], Wl + (size_t)n * KP + kt * 32 + g * 8);
  }

  const int lane = tid & 63, wv = tid >> 6;
  const int qr = lane >> 4, ml = lane & 15;
  const __bf16* wb[4];
  float bv[4];
  int wsw[4];
#pragma unroll
  for (int g = 0; g < 4; ++g) {
    const int n = g * 512 + j0 + ml;
    wb[g] = Wl + (size_t)n * KP + 512 + qr * 8;   // W_ih (L2-resident on this XCD)
    bv[g] = biasb[l * G4 + n];
    const int u = g * 16 + ml;
    wsw[g] = u * 32 + ((qr ^ ((u >> 1) & 3)) << 3);
  }
  const int r0 = (bx << 9) + (wv << 7);   // wave's 128 rows (8 m-tiles of 16)
  const int rowA = r0 + ml;
  // A-frag base offset into a slot: (kt*2 + (qr>>1))*16384 + row*16 + (qr&1)*8
  const int abase = ((qr >> 1) << 14) + rowA * 16 + ((qr & 1) << 3);
  __bf16* ringX  = hring  + (size_t)l * RS * SLOT;                     // l<7
  __bf16* ringHL = hringH + (size_t)l * 2 * SLOT;                      // l<7
  const __bf16* ringU = hring + (size_t)((l > 0 ? l : 1) - 1) * RS * SLOT;
  unsigned* ownf = flags + (l * 2 + bx) * 64;
  unsigned* upf  = flags + ((l > 0 ? l - 1 : 0) * 2 + bx) * 64;
  unsigned* dnf  = flags + ((l < 7 ? l + 1 : 7) * 2 + bx) * 64;
  float c8[8][4] = {};
  f32x4 acc[8][4];
  __syncthreads();  // W_hh staged

  auto initAcc = [&]() {
#pragma unroll
    for (int m = 0; m < 8; ++m)
#pragma unroll
      for (int g = 0; g < 4; ++g)
#pragma unroll
        for (int r = 0; r < 4; ++r) acc[m][g][r] = bv[g];
  };

  // x-part for layer 0: direct fp32->bf16 from x[:, tx, :], K=64
  auto xpartL0 = [&](int tx) {
#pragma unroll
    for (int m = 0; m < 8; ++m) {
      const float* xr = xf + ((size_t)(rowA + m * 16) * TT + tx) * IND + qr * 8;
      const f32x4 f0 = *(const f32x4*)xr;
      const f32x4 f1 = *(const f32x4*)(xr + 4);
      const f32x4 f2 = *(const f32x4*)(xr + 32);
      const f32x4 f3 = *(const f32x4*)(xr + 36);
      bf16x8 a0, a1;
#pragma unroll
      for (int r = 0; r < 4; ++r) {
        a0[r] = (__bf16)f0[r]; a0[4 + r] = (__bf16)f1[r];
        a1[r] = (__bf16)f2[r]; a1[4 + r] = (__bf16)f3[r];
      }
#pragma unroll
      for (int g = 0; g < 4; ++g) {
        acc[m][g] = __builtin_amdgcn_mfma_f32_16x16x32_bf16(
            a0, *(const bf16x8*)(wb[g]), acc[m][g], 0, 0, 0);
        acc[m][g] = __builtin_amdgcn_mfma_f32_16x16x32_bf16(
            a1, *(const bf16x8*)(wb[g] + 32), acc[m][g], 0, 0, 0);
      }
    }
  };

  // x-part for l>0: A = upstream h[tx], half-kt pipelined, W_ih 2-set rotation
  auto xpartL = [&](int tx) {
    const __bf16* src = ringU + (size_t)(tx & (RS - 1)) * SLOT + abase;
    bf16x8 A0[4], A1[4], Wr[2][4];
#pragma unroll
    for (int m = 0; m < 4; ++m) A0[m] = *(const bf16x8*)(src + m * 256);
#pragma unroll
    for (int m = 0; m < 4; ++m) A1[m] = *(const bf16x8*)(src + (4 + m) * 256);
#pragma unroll
    for (int g = 0; g < 4; ++g) Wr[0][g] = *(const bf16x8*)(wb[g]);
#pragma unroll
    for (int kt = 0; kt < 16; ++kt) {
      const __bf16* aknx = src + (kt + 1) * 32768;
#pragma unroll
      for (int m = 0; m < 4; ++m)
#pragma unroll
        for (int g = 0; g < 4; ++g)
          acc[m][g] = __builtin_amdgcn_mfma_f32_16x16x32_bf16(
              A0[m], Wr[kt & 1][g], acc[m][g], 0, 0, 0);
      if (kt < 15) {
#pragma unroll
        for (int m = 0; m < 4; ++m) A0[m] = *(const bf16x8*)(aknx + m * 256);
#pragma unroll
        for (int g = 0; g < 4; ++g)
          Wr[(kt + 1) & 1][g] = *(const bf16x8*)(wb[g] + (kt + 1) * 32);
      }
      __builtin_amdgcn_sched_barrier(0);
#pragma unroll
      for (int m = 0; m < 4; ++m)
#pragma unroll
        for (int g = 0; g < 4; ++g)
          acc[4 + m][g] = __builtin_amdgcn_mfma_f32_16x16x32_bf16(
              A1[m], Wr[kt & 1][g], acc[4 + m][g], 0, 0, 0);
      if (kt < 15) {
#pragma unroll
        for (int m = 0; m < 4; ++m) A1[m] = *(const bf16x8*)(aknx + (4 + m) * 256);
      }
      __builtin_amdgcn_sched_barrier(0);
    }
  };

  // h-part: A = own h[t-1] (ringH: L2-resident normal copy), half-kt pipelined
  auto hpart = [&](int t) {
    const __bf16* srcH = ((l < 7) ? ringHL + (size_t)((t - 1) & 1) * SLOT
                                  : h7 + (size_t)(t - 1) * SLOT) + abase;
    bf16x8 A0[4], A1[4];
#pragma unroll
    for (int m = 0; m < 4; ++m) A0[m] = *(const bf16x8*)(srcH + m * 256);
#pragma unroll
    for (int m = 0; m < 4; ++m) A1[m] = *(const bf16x8*)(srcH + (4 + m) * 256);
#pragma unroll
    for (int kt = 0; kt < 16; ++kt) {
      const __bf16* aknx = srcH + (kt + 1) * 32768;
      bf16x8 wf[4];
#pragma unroll
      for (int g = 0; g < 4; ++g) wf[g] = *(const bf16x8*)&Wlds[kt * 2048 + wsw[g]];
#pragma unroll
      for (int m = 0; m < 4; ++m)
#pragma unroll
        for (int g = 0; g < 4; ++g)
          acc[m][g] = __builtin_amdgcn_mfma_f32_16x16x32_bf16(
              A0[m], wf[g], acc[m][g], 0, 0, 0);
      if (kt < 15) {
#pragma unroll
        for (int m = 0; m < 4; ++m) A0[m] = *(const bf16x8*)(aknx + m * 256);
      }
      __builtin_amdgcn_sched_barrier(0);
#pragma unroll
      for (int m = 0; m < 4; ++m)
#pragma unroll
        for (int g = 0; g < 4; ++g)
          acc[4 + m][g] = __builtin_amdgcn_mfma_f32_16x16x32_bf16(
              A1[m], wf[g], acc[4 + m][g], 0, 0, 0);
      if (kt < 15) {
#pragma unroll
        for (int m = 0; m < 4; ++m) A1[m] = *(const bf16x8*)(aknx + (4 + m) * 256);
      }
      __builtin_amdgcn_sched_barrier(0);
    }
  };

  // ---- prologue: wait for upstream slot 0, compute x-part(0)
  if (l > 0) {
    if (wv == 0) {
      for (;;) {
        unsigned v = (lane < 32) ? __hip_atomic_load(upf + lane, __ATOMIC_RELAXED,
                                                     __HIP_MEMORY_SCOPE_AGENT)
                                 : 1u;
        if (__all((int)(v >= 1u))) break;
        __builtin_amdgcn_s_sleep(1);
      }
    }
    __syncthreads();
  }
  initAcc();
  if (l == 0) xpartL0(0); else xpartL(0);

  for (int t = 0; t < TT; ++t) {
    // ---- B1: own-recurrence wait (all 32 by-blocks of this (l,bx) at >= t)
    if (wv == 0 && t > 0) {
      const unsigned need = (unsigned)t;
      for (;;) {
        unsigned v = (lane < 32) ? __hip_atomic_load(ownf + lane, __ATOMIC_RELAXED,
                                                     __HIP_MEMORY_SCOPE_AGENT)
                                 : need;
        if (__all((int)(v >= need))) break;
        __builtin_amdgcn_s_sleep(1);
      }
    }
    __syncthreads();
    if (t > 0)
      __builtin_amdgcn_fence(__ATOMIC_ACQUIRE, "agent");  // per step: ringH 2-slot reuse

    // ---- h-part (t>0): acc already holds bias + x-part(t)
    if (t > 0) hpart(t);

    // ---- ring back-pressure (overwrite ringX slot t&7 only after downstream read gen t-8)
    if (wv == 0 && l < 7 && t >= RS) {
      const unsigned need = (unsigned)(t - (RS - 1));
      for (;;) {
        unsigned v = (lane < 32) ? __hip_atomic_load(dnf + lane, __ATOMIC_RELAXED,
                                                     __HIP_MEMORY_SCOPE_AGENT)
                                 : need;
        if (__all((int)(v >= need))) break;
        __builtin_amdgcn_s_sleep(1);
      }
    }
    __syncthreads();  // B2

    // ---- activations + dual h store: ringH (normal, own XCD) + ringX (agent)
    unsigned short* dstH = (unsigned short*)(((l < 7)
        ? ringHL + (size_t)(t & 1) * SLOT
        : h7 + (size_t)t * SLOT) + ((size_t)by << 14)) + ml;
    unsigned short* dstX = (l < 7)
        ? (unsigned short*)(ringX + (size_t)(t & (RS - 1)) * SLOT + ((size_t)by << 14)) + ml
        : nullptr;
#pragma unroll
    for (int m = 0; m < 8; ++m) {
      const int rbm = r0 + m * 16 + (qr << 2);
#pragma unroll
      for (int r = 0; r < 4; ++r) {
        const float gi = sigmf(acc[m][0][r]);
        const float gf = sigmf(acc[m][1][r]);
        const float gg = tanhfast(acc[m][2][r]);
        const float go = sigmf(acc[m][3][r]);
        const float cv = gf * c8[m][r] + gi * gg;
        c8[m][r] = cv;
        const unsigned short hb = __builtin_bit_cast(
            unsigned short, (__bf16)(go * tanhfast(cv)));
        dstH[(size_t)(rbm + r) * 16] = hb;           // normal -> local L2 (dirty)
        if (l < 7)
          __hip_atomic_store(dstX + (size_t)(rbm + r) * 16, hb,
                             __ATOMIC_RELAXED, __HIP_MEMORY_SCOPE_AGENT);
      }
    }
    __syncthreads();  // B3: drains vmcnt -> both store sets at coherence points
    if (tid == 0)
      __hip_atomic_store(ownf + by, (unsigned)(t + 1), __ATOMIC_RELAXED,
                         __HIP_MEMORY_SCOPE_AGENT);

    // ---- dead-zone work: x-part of step t+1 (covers flag propagation + tails)
    if (t + 1 < TT) {
      if (l > 0) {
        if (wv == 0) {
          const unsigned need = (unsigned)(t + 2);
          for (;;) {
            unsigned v = (lane < 32) ? __hip_atomic_load(upf + lane, __ATOMIC_RELAXED,
                                                         __HIP_MEMORY_SCOPE_AGENT)
                                     : need;
            if (__all((int)(v >= need))) break;
            __builtin_amdgcn_s_sleep(1);
          }
        }
        __syncthreads();
      }
      initAcc();
      if (l == 0) xpartL0(t + 1); else xpartL(t + 1);
    }
  }
}

// ---------------- FC (bf16 MFMA, K-split; h7 in [t][by][b][16] layout) ----------------
__global__ __launch_bounds__(256, 2) void fc_kernel(
    const __bf16* __restrict__ hseq, const __bf16* __restrict__ fcw,
    float* __restrict__ partial) {
  __shared__ __bf16 At[64 * 32];
  __shared__ __bf16 Wt[128 * 32];
  const int tid = threadIdx.x;
  const int b0 = blockIdx.x * 64;
  const int kbase = blockIdx.y * 2048;
  const int lane = tid & 63, wv = tid >> 6;
  const int qr = lane >> 4, ml = lane & 15;
  const int wr = (wv >> 1) * 32, wc = (wv & 1) * 64;
  const int sr = tid >> 2, sk = (tid & 3) * 8;

  f32x4 acc[2][4];
  for (int i = 0; i < 2; i++)
    for (int j = 0; j < 4; j++)
      for (int r = 0; r < 4; r++) acc[i][j][r] = 0.f;

  for (int kt = 0; kt < 64; ++kt) {
    const int k = kbase + kt * 32;
    const int t = k >> 9;
    const int kk = (k & 511) + sk;      // global j index of this 8-elem chunk
    gload16(&At[tid * 8],
            hseq + (size_t)t * SLOT + ((size_t)(kk >> 4) * 1024 + b0 + sr) * 16 + (kk & 15));
    gload16(&Wt[tid * 8],        fcw + (size_t)sr * (TT * HH) + k + sk);
    gload16(&Wt[2048 + tid * 8], fcw + (size_t)(sr + 64) * (TT * HH) + k + sk);
    __syncthreads();
    bf16x8 af[2], bfr[4];
    for (int i = 0; i < 2; i++) af[i]  = *(const bf16x8*)&At[(wr + i * 16 + ml) * 32 + qr * 8];
    for (int j = 0; j < 4; j++) bfr[j] = *(const bf16x8*)&Wt[(wc + j * 16 + ml) * 32 + qr * 8];
    for (int i = 0; i < 2; i++)
      for (int j = 0; j < 4; j++)
        acc[i][j] = __builtin_amdgcn_mfma_f32_16x16x32_bf16(af[i], bfr[j], acc[i][j], 0, 0, 0);
    __syncthreads();
  }
  for (int i = 0; i < 2; i++)
    for (int j = 0; j < 4; j++)
      for (int r = 0; r < 4; r++)
        partial[((size_t)blockIdx.y * BB + b0 + wr + i * 16 + qr * 4 + r) * NCLS + wc + j * 16 + ml] =
            acc[i][j][r];
}

__global__ void fc_reduce(const float* __restrict__ partial, const float* __restrict__ fcb,
                          float* __restrict__ out) {
  int i = blockIdx.x * 256 + threadIdx.x;  // B*128
  float s = fcb[i & 127];
  for (int p = 0; p < 16; p++) s += partial[(size_t)p * (BB * NCLS) + i];
  out[i] = s;
}

// ---------------- host ----------------
extern "C" void kernel_launch(void* const* d_in, const int* in_sizes, int n_in,
                              void* d_out, int out_size, void* d_ws, size_t ws_size,
                              hipStream_t stream) {
  const float* x    = (const float*)d_in[0];
  const float* wih0 = (const float*)d_in[1];
  const float* whh0 = (const float*)d_in[2];
  const float* bih0 = (const float*)d_in[3];
  const float* bhh0 = (const float*)d_in[4];
  const float* wih  = (const float*)d_in[5];
  const float* whh  = (const float*)d_in[6];
  const float* bih  = (const float*)d_in[7];
  const float* bhh  = (const float*)d_in[8];
  const float* fcw  = (const float*)d_in[9];
  const float* fcb  = (const float*)d_in[10];
  float* out = (float*)d_out;

  hipFuncSetAttribute((const void*)lstm_all,
                      hipFuncAttributeMaxDynamicSharedMemorySize, 65536);

  size_t off = 0;
  char* base = (char*)d_ws;
  auto carve = [&](size_t bytes) -> char* {
    char* p = base + off;
    off += (bytes + 255) & ~(size_t)255;
    return p;
  };
  // total ~191 MB (< proven 193 MB budget)
  __bf16*   Wp    = (__bf16*)carve((size_t)NLAYER * G4 * KP * 2);      // 33.6 MB
  __bf16*   fcwb  = (__bf16*)carve((size_t)NCLS * TT * HH * 2);        //  8.4 MB
  float*    biasb = (float*)carve((size_t)NLAYER * G4 * 4);
  __bf16*   hring = (__bf16*)carve((size_t)7 * RS * SLOT * 2);         // 58.7 MB
  __bf16*   hrinH = (__bf16*)carve((size_t)7 * 2 * SLOT * 2);          // 14.7 MB
  __bf16*   h7    = (__bf16*)carve((size_t)TT * SLOT * 2);             // 67.1 MB
  float*    part  = (float*)carve((size_t)16 * BB * NCLS * 4);         //  8.4 MB
  unsigned* flags = (unsigned*)carve((size_t)(NLAYER * 2 * 64 + 64) * 4);
  unsigned* xslot = flags + NLAYER * 2 * 64;

  // prep
  pack_w<<<(NLAYER * G4 * KP) / 256, 256, 0, stream>>>(whh0, wih0, whh, wih, Wp);
  cvt_kernel<<<(NCLS * TT * HH) / 256, 256, 0, stream>>>(fcw, fcwb, NCLS * TT * HH);
  bias_prep<<<(NLAYER * G4) / 256, 256, 0, stream>>>(bih0, bhh0, bih, bhh, biasb);
  zero_u32<<<(NLAYER * 2 * 64 + 64 + 255) / 256, 256, 0, stream>>>(
      flags, NLAYER * 2 * 64 + 64);

  lstm_all<<<512, 256, 65536, stream>>>(x, Wp, biasb, hring, hrinH, h7, flags, xslot);

  fc_kernel<<<dim3(16, 16), 256, 0, stream>>>(h7, fcwb, part);
  fc_reduce<<<(BB * NCLS) / 256, 256, 0, stream>>>(part, fcb, out);
}

// Round 7
// 3686.981 us; speedup vs baseline: 1.0669x; 1.0669x over previous
//
#include <hip/hip_runtime.h>
#include <hip/hip_bf16.h>

#define BB   1024
#define TT   64
#define IND  64
#define HH   512
#define G4   2048   // 4*H
#define NLAYER 8
#define NCLS 128
#define KP   1024   // packed W k-stride: k<512 = W_hh, k>=512 = W_ih (layer0 64 + pad)
#define RS   8      // ring slots per layer (reuse distance 8 = fence period)
#define SLOT (32 * 1024 * 16)  // elements per h slot: [by=32][b=1024][jj=16]

typedef __bf16 bf16x8 __attribute__((ext_vector_type(8)));
typedef float  f32x4  __attribute__((ext_vector_type(4)));

typedef const __attribute__((address_space(1))) void* as1cvp;
typedef __attribute__((address_space(3))) void* as3vp;

__device__ __forceinline__ void gload16(void* lds, const void* g) {
  __builtin_amdgcn_global_load_lds((as1cvp)g, (as3vp)lds, 16, 0, 0);
}

__device__ __forceinline__ float sigmf(float x) { return 1.f / (1.f + __expf(-x)); }
__device__ __forceinline__ float tanhfast(float x) { return 2.f / (1.f + __expf(-2.f * x)) - 1.f; }

// ---------------- prep kernels ----------------
__global__ void cvt_kernel(const float* __restrict__ s, __bf16* __restrict__ d, int n) {
  int i = blockIdx.x * 256 + threadIdx.x;
  if (i < n) d[i] = (__bf16)s[i];
}

__global__ void pack_w(const float* __restrict__ whh0, const float* __restrict__ wih0,
                       const float* __restrict__ whh, const float* __restrict__ wih,
                       __bf16* __restrict__ Wp) {
  int i = blockIdx.x * 256 + threadIdx.x;  // 8*2048*1024
  int k = i & (KP - 1), n = (i >> 10) & 2047, l = i >> 21;
  float v;
  if (k < 512) v = (l == 0) ? whh0[n * 512 + k] : whh[((size_t)(l - 1) * G4 + n) * 512 + k];
  else if (l == 0) v = (k < 512 + IND) ? wih0[n * IND + (k - 512)] : 0.f;
  else v = wih[((size_t)(l - 1) * G4 + n) * 512 + (k - 512)];
  Wp[i] = (__bf16)v;
}

__global__ void bias_prep(const float* __restrict__ bi0, const float* __restrict__ bh0,
                          const float* __restrict__ bi, const float* __restrict__ bh,
                          float* __restrict__ biasb) {
  int i = blockIdx.x * 256 + threadIdx.x;  // 8*2048
  int l = i >> 11, k = i & 2047;
  float v = (l == 0) ? (bi0[k] + bh0[k]) : (bi[(l - 1) * G4 + k] + bh[(l - 1) * G4 + k]);
  biasb[i] = v;
}

__global__ void zero_u32(unsigned* __restrict__ p, int n) {
  int i = blockIdx.x * 256 + threadIdx.x;
  if (i < n) p[i] = 0u;
}

// ---------------- all-layers pipelined LSTM ----------------
// R17 = R14 (proven 3643us) with ALL per-step __syncthreads removed.
// Rationale: R14's cadence carried 4 block barriers + 3 wave0-centralized
// polls per step; each s_barrier full-drains all waves and couples the 4
// waves into lock-step (R16 showed cache-scope surgery is not the lever;
// sync overhead is). Key fact: the 4 waves of a block NEVER share per-step
// data — wave wv reads A-rows r0(bx,wv), produced exclusively by wave wv of
// the 32 by-blocks of the (l,bx) group (h-part) or of the upstream group
// (x-part). Only W_hh LDS is shared, and it is read-only after staging.
// So: flags become per-(by,wv): flags[l][bx][wv][32 by]. Every wave
//  - polls its own 32 producer flags (32 lanes, 1 load each),
//  - sets its own flag after a wave-local s_waitcnt vmcnt(0),
//  - fences (acquire-agent) once per RS=8 ring period,
// and no step-level block barrier exists at all. 2048 independent wave
// pipelines; SIMD-mates (from 2 different blocks) drift and cover each
// other's stalls instead of stalling together. Invariants unchanged:
// own>=t before h-part(t); down>=t-7 before overwriting ringX slot t&7;
// up>=t+2 before early x-part(t+1); any ring address re-read 8 steps apart
// straddles exactly one top-of-step fence (argument is per-wave now).
// Compiler load-hoisting across polls (previously blocked by barriers) is
// blocked with asm memory clobbers + sched_barrier(0).
// Same MFMA order and values -> bit-identical numerics to R14.
__global__ __launch_bounds__(256, 2) void lstm_all(
    const float* __restrict__ xf,      // [B][T][64] fp32
    const __bf16* __restrict__ Wp,     // [8][2048][KP]
    const float* __restrict__ biasb,   // [8][2048]
    __bf16* __restrict__ hring,        // [7][RS][SLOT]
    __bf16* __restrict__ h7,           // [64][SLOT]
    unsigned* __restrict__ flags,      // [8][2][4][32] per-(l,bx,wv,by)
    unsigned* __restrict__ xslot) {    // [8]
  extern __shared__ __bf16 Wlds[];     // 64KB: 16 k-slices x (64 rows x 32 k)
  __shared__ int sbs;
  const int tid = threadIdx.x;

  if (tid == 0) {
    unsigned xcc;
    asm volatile("s_getreg_b32 %0, hwreg(HW_REG_XCC_ID)" : "=s"(xcc));
    xcc &= 7u;
    unsigned slot = __hip_atomic_fetch_add(xslot + xcc, 1u, __ATOMIC_RELAXED,
                                           __HIP_MEMORY_SCOPE_AGENT) & 63u;
    sbs = (int)((xcc << 6) | slot);
  }
  __syncthreads();
  const int l  = sbs >> 6;         // layer = XCD
  const int bx = (sbs >> 5) & 1;   // b-half (512 rows)
  const int by = sbs & 31;         // j-tile (16 j x 4 gates)
  const int j0 = by << 4;
  const __bf16* Wl = Wp + (size_t)l * G4 * KP;

  // ---- stage W_hh (64 n-rows x 512 k) into LDS, XOR-swizzled
  for (int it = 0; it < 16; ++it) {
    const int p = it * 256 + tid;           // granule 0..4095
    const int kt = p >> 8;
    const int q = p & 255;
    const int u = q >> 2;                   // row 0..63 (gate*16+jj)
    const int g = (q & 3) ^ ((u >> 1) & 3);
    const int n = ((u >> 4) << 9) + j0 + (u & 15);
    gload16(&Wlds[p * 8], Wl + (size_t)n * KP + kt * 32 + g * 8);
  }

  const int lane = tid & 63, wv = tid >> 6;
  const int qr = lane >> 4, ml = lane & 15;
  const __bf16* wb[4];
  float bv[4];
  int wsw[4];
#pragma unroll
  for (int g = 0; g < 4; ++g) {
    const int n = g * 512 + j0 + ml;
    wb[g] = Wl + (size_t)n * KP + 512 + qr * 8;   // W_ih (L2-resident on this XCD)
    bv[g] = biasb[l * G4 + n];
    const int u = g * 16 + ml;
    wsw[g] = u * 32 + ((qr ^ ((u >> 1) & 3)) << 3);
  }
  const int r0 = (bx << 9) + (wv << 7);   // wave's 128 rows (8 m-tiles of 16)
  const int rowA = r0 + ml;
  // A-frag base offset into a slot: (kt*2 + (qr>>1))*16384 + row*16 + (qr&1)*8
  const int abase = ((qr >> 1) << 14) + rowA * 16 + ((qr & 1) << 3);
  __bf16* ringL = hring + (size_t)l * RS * SLOT;                       // l<7
  const __bf16* ringU = hring + (size_t)((l > 0 ? l : 1) - 1) * RS * SLOT;
  // per-(by,wv) flags: group stride 4*32, wave stride 32
  unsigned* ownfw = flags + ((l * 2 + bx) * 4 + wv) * 32;
  unsigned* upfw  = flags + (((l > 0 ? l - 1 : 0) * 2 + bx) * 4 + wv) * 32;
  unsigned* dnfw  = flags + (((l < 7 ? l + 1 : 7) * 2 + bx) * 4 + wv) * 32;
  float c8[8][4] = {};
  f32x4 acc[8][4];
  __syncthreads();  // W_hh staged (drains staging vmcnt); last block barrier

  // per-wave poll: 32 producer flags, one load per lane; compiler fence after
  auto pollge = [&](const unsigned* fp, unsigned need) {
    for (;;) {
      unsigned v = (lane < 32) ? __hip_atomic_load(fp + lane, __ATOMIC_RELAXED,
                                                   __HIP_MEMORY_SCOPE_AGENT)
                               : need;
      if (__all((int)(v >= need))) break;
      __builtin_amdgcn_s_sleep(1);
    }
    asm volatile("" ::: "memory");
    __builtin_amdgcn_sched_barrier(0);
  };

  auto initAcc = [&]() {
#pragma unroll
    for (int m = 0; m < 8; ++m)
#pragma unroll
      for (int g = 0; g < 4; ++g)
#pragma unroll
        for (int r = 0; r < 4; ++r) acc[m][g][r] = bv[g];
  };

  // x-part for layer 0: direct fp32->bf16 from x[:, tx, :], K=64
  auto xpartL0 = [&](int tx) {
#pragma unroll
    for (int m = 0; m < 8; ++m) {
      const float* xr = xf + ((size_t)(rowA + m * 16) * TT + tx) * IND + qr * 8;
      const f32x4 f0 = *(const f32x4*)xr;
      const f32x4 f1 = *(const f32x4*)(xr + 4);
      const f32x4 f2 = *(const f32x4*)(xr + 32);
      const f32x4 f3 = *(const f32x4*)(xr + 36);
      bf16x8 a0, a1;
#pragma unroll
      for (int r = 0; r < 4; ++r) {
        a0[r] = (__bf16)f0[r]; a0[4 + r] = (__bf16)f1[r];
        a1[r] = (__bf16)f2[r]; a1[4 + r] = (__bf16)f3[r];
      }
#pragma unroll
      for (int g = 0; g < 4; ++g) {
        acc[m][g] = __builtin_amdgcn_mfma_f32_16x16x32_bf16(
            a0, *(const bf16x8*)(wb[g]), acc[m][g], 0, 0, 0);
        acc[m][g] = __builtin_amdgcn_mfma_f32_16x16x32_bf16(
            a1, *(const bf16x8*)(wb[g] + 32), acc[m][g], 0, 0, 0);
      }
    }
  };

  // x-part for l>0: A = upstream h[tx], half-kt pipelined, W_ih 2-set rotation
  auto xpartL = [&](int tx) {
    const __bf16* src = ringU + (size_t)(tx & (RS - 1)) * SLOT + abase;
    bf16x8 A0[4], A1[4], Wr[2][4];
#pragma unroll
    for (int m = 0; m < 4; ++m) A0[m] = *(const bf16x8*)(src + m * 256);
#pragma unroll
    for (int m = 0; m < 4; ++m) A1[m] = *(const bf16x8*)(src + (4 + m) * 256);
#pragma unroll
    for (int g = 0; g < 4; ++g) Wr[0][g] = *(const bf16x8*)(wb[g]);
#pragma unroll
    for (int kt = 0; kt < 16; ++kt) {
      const __bf16* aknx = src + (kt + 1) * 32768;
#pragma unroll
      for (int m = 0; m < 4; ++m)
#pragma unroll
        for (int g = 0; g < 4; ++g)
          acc[m][g] = __builtin_amdgcn_mfma_f32_16x16x32_bf16(
              A0[m], Wr[kt & 1][g], acc[m][g], 0, 0, 0);
      if (kt < 15) {
#pragma unroll
        for (int m = 0; m < 4; ++m) A0[m] = *(const bf16x8*)(aknx + m * 256);
#pragma unroll
        for (int g = 0; g < 4; ++g)
          Wr[(kt + 1) & 1][g] = *(const bf16x8*)(wb[g] + (kt + 1) * 32);
      }
      __builtin_amdgcn_sched_barrier(0);
#pragma unroll
      for (int m = 0; m < 4; ++m)
#pragma unroll
        for (int g = 0; g < 4; ++g)
          acc[4 + m][g] = __builtin_amdgcn_mfma_f32_16x16x32_bf16(
              A1[m], Wr[kt & 1][g], acc[4 + m][g], 0, 0, 0);
      if (kt < 15) {
#pragma unroll
        for (int m = 0; m < 4; ++m) A1[m] = *(const bf16x8*)(aknx + (4 + m) * 256);
      }
      __builtin_amdgcn_sched_barrier(0);
    }
  };

  // h-part: A = own h[t-1], half-kt pipelined, W_hh JIT from LDS
  auto hpart = [&](int t) {
    const __bf16* srcH = ((l < 7) ? ringL + (size_t)((t - 1) & (RS - 1)) * SLOT
                                  : h7 + (size_t)(t - 1) * SLOT) + abase;
    bf16x8 A0[4], A1[4];
#pragma unroll
    for (int m = 0; m < 4; ++m) A0[m] = *(const bf16x8*)(srcH + m * 256);
#pragma unroll
    for (int m = 0; m < 4; ++m) A1[m] = *(const bf16x8*)(srcH + (4 + m) * 256);
#pragma unroll
    for (int kt = 0; kt < 16; ++kt) {
      const __bf16* aknx = srcH + (kt + 1) * 32768;
      bf16x8 wf[4];
#pragma unroll
      for (int g = 0; g < 4; ++g) wf[g] = *(const bf16x8*)&Wlds[kt * 2048 + wsw[g]];
#pragma unroll
      for (int m = 0; m < 4; ++m)
#pragma unroll
        for (int g = 0; g < 4; ++g)
          acc[m][g] = __builtin_amdgcn_mfma_f32_16x16x32_bf16(
              A0[m], wf[g], acc[m][g], 0, 0, 0);
      if (kt < 15) {
#pragma unroll
        for (int m = 0; m < 4; ++m) A0[m] = *(const bf16x8*)(aknx + m * 256);
      }
      __builtin_amdgcn_sched_barrier(0);
#pragma unroll
      for (int m = 0; m < 4; ++m)
#pragma unroll
        for (int g = 0; g < 4; ++g)
          acc[4 + m][g] = __builtin_amdgcn_mfma_f32_16x16x32_bf16(
              A1[m], wf[g], acc[4 + m][g], 0, 0, 0);
      if (kt < 15) {
#pragma unroll
        for (int m = 0; m < 4; ++m) A1[m] = *(const bf16x8*)(aknx + (4 + m) * 256);
      }
      __builtin_amdgcn_sched_barrier(0);
    }
  };

  // ---- prologue: wait for upstream slot 0 (per-wave), compute x-part(0)
  if (l > 0) pollge(upfw, 1u);
  initAcc();
  if (l == 0) xpartL0(0); else xpartL(0);

  for (int t = 0; t < TT; ++t) {
    // ---- own-recurrence wait (wave wv of all 32 by-blocks at >= t)
    if (t > 0) {
      pollge(ownfw, (unsigned)t);
      if ((t & (RS - 1)) == 0)
        __builtin_amdgcn_fence(__ATOMIC_ACQUIRE, "agent");  // once per ring period
      hpart(t);
    }

    // ---- ring back-pressure (overwrite slot t&7 only after downstream read gen t-8)
    if (l < 7 && t >= RS) pollge(dnfw, (unsigned)(t - (RS - 1)));

    // ---- activations + h store: [by][b][16] panel -> contiguous 32B granules
    unsigned short* dst = (unsigned short*)(((l < 7)
        ? ringL + (size_t)(t & (RS - 1)) * SLOT
        : h7 + (size_t)t * SLOT) + ((size_t)by << 14)) + ml;
#pragma unroll
    for (int m = 0; m < 8; ++m) {
      const int rbm = r0 + m * 16 + (qr << 2);
#pragma unroll
      for (int r = 0; r < 4; ++r) {
        const float gi = sigmf(acc[m][0][r]);
        const float gf = sigmf(acc[m][1][r]);
        const float gg = tanhfast(acc[m][2][r]);
        const float go = sigmf(acc[m][3][r]);
        const float cv = gf * c8[m][r] + gi * gg;
        c8[m][r] = cv;
        const __bf16 hv = (__bf16)(go * tanhfast(cv));
        __hip_atomic_store(dst + (size_t)(rbm + r) * 16,
                           __builtin_bit_cast(unsigned short, hv),
                           __ATOMIC_RELAXED, __HIP_MEMORY_SCOPE_AGENT);
      }
    }
    // ---- wave-local drain + per-wave flag (replaces B3 barrier)
    asm volatile("s_waitcnt vmcnt(0)" ::: "memory");
    __builtin_amdgcn_sched_barrier(0);
    if (lane == 0)
      __hip_atomic_store(ownfw + by, (unsigned)(t + 1), __ATOMIC_RELAXED,
                         __HIP_MEMORY_SCOPE_AGENT);

    // ---- dead-zone work: x-part of step t+1 (covers flag propagation + tails)
    if (t + 1 < TT) {
      if (l > 0) pollge(upfw, (unsigned)(t + 2));
      initAcc();
      if (l == 0) xpartL0(t + 1); else xpartL(t + 1);
    }
  }
}

// ---------------- FC (bf16 MFMA, K-split; h7 in [t][by][b][16] layout) ----------------
__global__ __launch_bounds__(256, 2) void fc_kernel(
    const __bf16* __restrict__ hseq, const __bf16* __restrict__ fcw,
    float* __restrict__ partial) {
  __shared__ __bf16 At[64 * 32];
  __shared__ __bf16 Wt[128 * 32];
  const int tid = threadIdx.x;
  const int b0 = blockIdx.x * 64;
  const int kbase = blockIdx.y * 2048;
  const int lane = tid & 63, wv = tid >> 6;
  const int qr = lane >> 4, ml = lane & 15;
  const int wr = (wv >> 1) * 32, wc = (wv & 1) * 64;
  const int sr = tid >> 2, sk = (tid & 3) * 8;

  f32x4 acc[2][4];
  for (int i = 0; i < 2; i++)
    for (int j = 0; j < 4; j++)
      for (int r = 0; r < 4; r++) acc[i][j][r] = 0.f;

  for (int kt = 0; kt < 64; ++kt) {
    const int k = kbase + kt * 32;
    const int t = k >> 9;
    const int kk = (k & 511) + sk;      // global j index of this 8-elem chunk
    gload16(&At[tid * 8],
            hseq + (size_t)t * SLOT + ((size_t)(kk >> 4) * 1024 + b0 + sr) * 16 + (kk & 15));
    gload16(&Wt[tid * 8],        fcw + (size_t)sr * (TT * HH) + k + sk);
    gload16(&Wt[2048 + tid * 8], fcw + (size_t)(sr + 64) * (TT * HH) + k + sk);
    __syncthreads();
    bf16x8 af[2], bfr[4];
    for (int i = 0; i < 2; i++) af[i]  = *(const bf16x8*)&At[(wr + i * 16 + ml) * 32 + qr * 8];
    for (int j = 0; j < 4; j++) bfr[j] = *(const bf16x8*)&Wt[(wc + j * 16 + ml) * 32 + qr * 8];
    for (int i = 0; i < 2; i++)
      for (int j = 0; j < 4; j++)
        acc[i][j] = __builtin_amdgcn_mfma_f32_16x16x32_bf16(af[i], bfr[j], acc[i][j], 0, 0, 0);
    __syncthreads();
  }
  for (int i = 0; i < 2; i++)
    for (int j = 0; j < 4; j++)
      for (int r = 0; r < 4; r++)
        partial[((size_t)blockIdx.y * BB + b0 + wr + i * 16 + qr * 4 + r) * NCLS + wc + j * 16 + ml] =
            acc[i][j][r];
}

__global__ void fc_reduce(const float* __restrict__ partial, const float* __restrict__ fcb,
                          float* __restrict__ out) {
  int i = blockIdx.x * 256 + threadIdx.x;  // B*128
  float s = fcb[i & 127];
  for (int p = 0; p < 16; p++) s += partial[(size_t)p * (BB * NCLS) + i];
  out[i] = s;
}

// ---------------- host ----------------
extern "C" void kernel_launch(void* const* d_in, const int* in_sizes, int n_in,
                              void* d_out, int out_size, void* d_ws, size_t ws_size,
                              hipStream_t stream) {
  const float* x    = (const float*)d_in[0];
  const float* wih0 = (const float*)d_in[1];
  const float* whh0 = (const float*)d_in[2];
  const float* bih0 = (const float*)d_in[3];
  const float* bhh0 = (const float*)d_in[4];
  const float* wih  = (const float*)d_in[5];
  const float* whh  = (const float*)d_in[6];
  const float* bih  = (const float*)d_in[7];
  const float* bhh  = (const float*)d_in[8];
  const float* fcw  = (const float*)d_in[9];
  const float* fcb  = (const float*)d_in[10];
  float* out = (float*)d_out;

  hipFuncSetAttribute((const void*)lstm_all,
                      hipFuncAttributeMaxDynamicSharedMemorySize, 65536);

  size_t off = 0;
  char* base = (char*)d_ws;
  auto carve = [&](size_t bytes) -> char* {
    char* p = base + off;
    off += (bytes + 255) & ~(size_t)255;
    return p;
  };
  // total ~176 MB (< proven 193 MB budget)
  __bf16*   Wp    = (__bf16*)carve((size_t)NLAYER * G4 * KP * 2);      // 33.6 MB
  __bf16*   fcwb  = (__bf16*)carve((size_t)NCLS * TT * HH * 2);        //  8.4 MB
  float*    biasb = (float*)carve((size_t)NLAYER * G4 * 4);
  __bf16*   hring = (__bf16*)carve((size_t)7 * RS * SLOT * 2);         // 58.7 MB
  __bf16*   h7    = (__bf16*)carve((size_t)TT * SLOT * 2);             // 67.1 MB
  float*    part  = (float*)carve((size_t)16 * BB * NCLS * 4);         //  8.4 MB
  unsigned* flags = (unsigned*)carve((size_t)(NLAYER * 2 * 4 * 32 + 64) * 4);
  unsigned* xslot = flags + NLAYER * 2 * 4 * 32;

  // prep
  pack_w<<<(NLAYER * G4 * KP) / 256, 256, 0, stream>>>(whh0, wih0, whh, wih, Wp);
  cvt_kernel<<<(NCLS * TT * HH) / 256, 256, 0, stream>>>(fcw, fcwb, NCLS * TT * HH);
  bias_prep<<<(NLAYER * G4) / 256, 256, 0, stream>>>(bih0, bhh0, bih, bhh, biasb);
  zero_u32<<<(NLAYER * 2 * 4 * 32 + 64 + 255) / 256, 256, 0, stream>>>(
      flags, NLAYER * 2 * 4 * 32 + 64);

  lstm_all<<<512, 256, 65536, stream>>>(x, Wp, biasb, hring, h7, flags, xslot);

  fc_kernel<<<dim3(16, 16), 256, 0, stream>>>(h7, fcwb, part);
  fc_reduce<<<(BB * NCLS) / 256, 256, 0, stream>>>(part, fcb, out);
}